// Round 7
// baseline (493.646 us; speedup 1.0000x reference)
//
#include <hip/hip_runtime.h>
#include <stdint.h>

// Problem constants
constexpr int CIN  = 32;
constexpr int COLS_PER_B = 8192;               // COUT*ATOM
constexpr long long NTOT = 1048576;            // B * COLS_PER_B columns
constexpr float NTOTF = 1048576.0f;

typedef float f32x2 __attribute__((ext_vector_type(2)));

// Stats kernel tiling
constexpr int PADS  = 272;   // row stride floats; 272%32==16 -> (pr&1,kg) bank split, 2-way max (free)
constexpr int GRID1 = 512;   // 2 blocks/CU (69.8 KB LDS each)
constexpr int TPB   = 8;     // 4096 tiles / 512 blocks

// ws layout (floats): [0..1023] G accum, [1024..1055] s accum,
//                     [1056..2079] W (invsqrt*gamma), [2080..2111] bias

__global__ __launch_bounds__(512, 4) void stats_kernel(const float* __restrict__ x,
                                                       float* __restrict__ acc) {
    __shared__ float tile[2][CIN][PADS];   // 69,632 B double buffer
    __shared__ float ssum[CIN];
    const int t   = threadIdx.x;
    const int w   = t >> 6;        // wave 0..7
    const int l   = t & 63;
    const int kg  = l >> 4;        // k-subgroup 0..3
    const int pos = l & 15;
    const int pr  = pos >> 2;      // 0..3 -> A rows {pr+4d}
    const int pc  = pos & 3;       // 0..3 -> B rows {pc+4e}
    const int g   = w * 4 + kg;    // global k-group 0..31

    float accg[8][8] = {};
    float asum[8] = {};
    if (t < CIN) ssum[t] = 0.f;

    const int tile0 = blockIdx.x * TPB;

    // Async global->LDS staging (no VGPR round-trip; r4's reg-prefetch spilled).
    // Wave w stages rows 4w..4w+3; lanes write contiguous 16B chunks of a row.
    auto stage = [&](int buf, int tileid) {
        const int b = tileid >> 5;               // 32 tiles per batch
        const int col0 = (tileid & 31) << 8;     // *256
        const float* base = x + (size_t)b * CIN * COLS_PER_B + col0 + l * 4;
        #pragma unroll
        for (int rr = 0; rr < 4; ++rr) {
            const int row = w * 4 + rr;
            const float* gp = base + (size_t)row * COLS_PER_B;
            __builtin_amdgcn_global_load_lds(
                (const __attribute__((address_space(1))) uint32_t*)gp,
                (__attribute__((address_space(3))) uint32_t*)&tile[buf][row][0],
                16, 0, 0);
        }
    };

    stage(0, tile0);
    __syncthreads();            // tile0 resident (also covers ssum init)

    int buf = 0;
    for (int tt = 0; tt < TPB; ++tt) {
        if (tt + 1 < TPB) stage(buf ^ 1, tile0 + tt + 1);   // in flight during compute
        // 32-way k-split: group g covers float4-steps {g, g+32} of 64
        #pragma unroll
        for (int s = 0; s < 2; ++s) {
            const int k0 = g * 4 + s * 128;
            float4 bvv[8];
            #pragma unroll
            for (int e = 0; e < 8; ++e) bvv[e] = *(const float4*)&tile[buf][pc + 4 * e][k0];
            #pragma unroll
            for (int d = 0; d < 8; ++d) {
                const float4 a = *(const float4*)&tile[buf][pr + 4 * d][k0];
                asum[d] += a.x + a.y + a.z + a.w;
                #pragma unroll
                for (int e = 0; e < 8; ++e) {
                    accg[d][e] += a.x * bvv[e].x + a.y * bvv[e].y
                                + a.z * bvv[e].z + a.w * bvv[e].w;
                }
            }
        }
        __syncthreads();   // readers done with buf; next-tile loads drained
        buf ^= 1;
    }

    // reduce k-subgroups (kg = lane bits 4-5) via butterfly shuffles
    #pragma unroll
    for (int d = 0; d < 8; ++d) {
        #pragma unroll
        for (int e = 0; e < 8; ++e) {
            float v = accg[d][e];
            v += __shfl_xor(v, 16, 64);
            v += __shfl_xor(v, 32, 64);
            accg[d][e] = v;
        }
        float u = asum[d];
        u += __shfl_xor(u, 16, 64);
        u += __shfl_xor(u, 32, 64);
        asum[d] = u;
    }

    // cross-wave reduction via LDS (reuse tile as flat scratch; all waves have
    // passed the final loop barrier, no further tile reads)
    float* flat = &tile[0][0][0];
    if (kg == 0) {
        #pragma unroll
        for (int d = 0; d < 8; ++d)
            #pragma unroll
            for (int e = 0; e < 8; ++e)
                flat[w * 1024 + (pr + 4 * d) * 32 + (pc + 4 * e)] = accg[d][e];
        if (pc == 0) {
            #pragma unroll
            for (int d = 0; d < 8; ++d) atomicAdd(&ssum[pr + 4 * d], asum[d]);
        }
    }
    __syncthreads();
    #pragma unroll
    for (int q = 0; q < 2; ++q) {
        const int idx = t + q * 512;
        float v = 0.f;
        #pragma unroll
        for (int ww = 0; ww < 8; ++ww) v += flat[ww * 1024 + idx];
        atomicAdd(&acc[idx], v);
    }
    if (t < CIN) atomicAdd(&acc[1024 + t], ssum[t]);
}

__global__ __launch_bounds__(1024) void newton_kernel(const float* __restrict__ acc,
                                                      const float* __restrict__ gamma,
                                                      const float* __restrict__ beta,
                                                      float* __restrict__ outp) {
    __shared__ float sn[32 * 33], p[32 * 33], t1[32 * 33], t2[32 * 33];
    __shared__ float mean[32], diag[32], trs[1];
    const int t = threadIdx.x;
    const int i = t >> 5, j = t & 31;

    if (t < 32) mean[t] = acc[1024 + t] * (1.0f / NTOTF);
    __syncthreads();
    const float sig = (acc[t] - NTOTF * mean[i] * mean[j]) * (1.0f / (NTOTF - 1.0f));
    if (i == j) diag[i] = sig;
    __syncthreads();
    if (t == 0) {
        float tr = 0.f;
        for (int k = 0; k < 32; ++k) tr += diag[k];
        trs[0] = tr;
    }
    __syncthreads();
    const float tr = trs[0];
    sn[i * 33 + j] = sig / tr;
    p[i * 33 + j]  = (i == j) ? 1.0f : 0.0f;
    __syncthreads();

    for (int it = 0; it < 5; ++it) {
        // P^3*Sn = (P*P) @ (P*Sn): both sub-products in one phase (3 barriers/iter)
        float a = 0.f, c = 0.f;
        #pragma unroll
        for (int k = 0; k < 32; ++k) {
            const float pik = p[i * 33 + k];
            a += pik * p[k * 33 + j];
            c += pik * sn[k * 33 + j];
        }
        t1[i * 33 + j] = a;
        t2[i * 33 + j] = c;
        __syncthreads();
        float v = 0.f;
        #pragma unroll
        for (int k = 0; k < 32; ++k) v += t1[i * 33 + k] * t2[k * 33 + j];
        const float pn = 1.5f * p[i * 33 + j] - 0.5f * v;
        __syncthreads();
        p[i * 33 + j] = pn;
        __syncthreads();
    }

    const float r = rsqrtf(tr);
    const float wv = p[i * 33 + j] * r * gamma[j];   // fold gamma into W
    t1[i * 33 + j] = wv;
    outp[t] = wv;                                    // W: 1024 floats
    __syncthreads();
    if (t < 32) {
        float bb = beta[t];
        for (int k = 0; k < 32; ++k) bb -= mean[k] * t1[k * 33 + t];
        outp[1024 + t] = bb;                         // bias: 32 floats
    }
}

// W via constant address space -> uniform s_load into SGPRs; inner loop is
// pure v_fmac_f32 v, s, v (no per-use VMEM/VALU for W).
typedef const __attribute__((address_space(4))) float cfloat;

__global__ __launch_bounds__(256, 4) void apply_kernel(const float* __restrict__ x,
                                                       const float* __restrict__ wmp,
                                                       float* __restrict__ out) {
    cfloat* wm = (cfloat*)wmp;
    const size_t tid  = (size_t)blockIdx.x * 256 + threadIdx.x;
    const size_t col2 = tid * 2;          // 2 columns per thread
    const size_t b    = col2 >> 13;       // /8192
    const size_t c    = col2 & 8191;
    const float* xp = x + b * (size_t)(CIN * COLS_PER_B) + c;
    float* op       = out + b * (size_t)(CIN * COLS_PER_B) + c;

    float2 accv[32];
    #pragma unroll
    for (int j = 0; j < 32; ++j) {
        const float bv = wm[1024 + j];
        accv[j] = make_float2(bv, bv);
    }
    #pragma unroll
    for (int i = 0; i < 32; ++i) {
        const float2 v = *(const float2*)(xp + (size_t)i * COLS_PER_B);
        #pragma unroll
        for (int j = 0; j < 32; ++j) {
            const float sv = wm[i * 32 + j];  // SGPR operand
            accv[j].x += v.x * sv;
            accv[j].y += v.y * sv;
        }
    }
    // Nontemporal: out is write-once; don't evict L3-resident x.
    #pragma unroll
    for (int j = 0; j < 32; ++j) {
        f32x2 v = { accv[j].x, accv[j].y };
        __builtin_nontemporal_store(v, (f32x2*)(op + (size_t)j * COLS_PER_B));
    }
}

extern "C" void kernel_launch(void* const* d_in, const int* in_sizes, int n_in,
                              void* d_out, int out_size, void* d_ws, size_t ws_size,
                              hipStream_t stream) {
    const float* x     = (const float*)d_in[0];
    const float* gamma = (const float*)d_in[1];
    const float* beta  = (const float*)d_in[2];
    float* out = (float*)d_out;
    float* acc = (float*)d_ws;            // 1056 accum + 1056 result floats

    (void)hipMemsetAsync(acc, 0, 1056 * sizeof(float), stream);
    stats_kernel<<<GRID1, 512, 0, stream>>>(x, acc);
    newton_kernel<<<1, 1024, 0, stream>>>(acc, gamma, beta, acc + 1056);
    apply_kernel<<<(NTOT / 2) / 256, 256, 0, stream>>>(x, acc + 1056, out);
}